// Round 7
// baseline (423.242 us; speedup 1.0000x reference)
//
#include <hip/hip_runtime.h>
#include <hip/hip_bf16.h>
#include <math.h>

#define DIM 768
#define NH 12
#define HD 64
#define BATCH 16
#define SEQ 1024
#define M_TOTAL (BATCH * SEQ)   // 16384
#define MATE ((size_t)M_TOTAL * DIM)  // elements per activation plane

typedef unsigned short ushort_t;
typedef __attribute__((ext_vector_type(8))) short short8;
typedef __attribute__((ext_vector_type(4))) float floatx4;

__device__ __constant__ float kScale = 0.03608439182435161f; // 1/sqrt(768)

__device__ inline ushort_t f2b(float x) {
    __hip_bfloat16 h = __float2bfloat16(x);
    return __builtin_bit_cast(ushort_t, h);
}
__device__ inline float b2f_u32(unsigned int bits16) {
    union { unsigned int i; float f; } c;
    c.i = bits16 << 16;
    return c.f;
}
__device__ inline float b2f(ushort_t u) { return b2f_u32((unsigned int)u); }

// async global->LDS, 16 B per lane; LDS dest is wave-uniform base + lane*16
__device__ __forceinline__ void gl2lds16(const ushort_t* g, ushort_t* l) {
    __builtin_amdgcn_global_load_lds(
        (__attribute__((address_space(1))) void*)g,
        (__attribute__((address_space(3))) void*)l, 16, 0, 0);
}

// ---------------------------------------------------------------------------
// fp32 -> bf16 plane
// ---------------------------------------------------------------------------
__global__ __launch_bounds__(256) void cvt_bf16_kernel(
    const float* __restrict__ X, ushort_t* __restrict__ Y, int n4)
{
    int i = blockIdx.x * 256 + threadIdx.x;
    if (i >= n4) return;
    float4 v = ((const float4*)X)[i];
    ushort4 o;
    o.x = f2b(v.x); o.y = f2b(v.y); o.z = f2b(v.z); o.w = f2b(v.w);
    ((ushort4*)Y)[i] = o;
}

// ---------------------------------------------------------------------------
// All 4 weights: W[k][n] fp32 -> transposed bf16 plane Wt[n][k].
// blockIdx.z selects the matrix (0=Wq,1=Wk,2=Wv,3=Wo).
// ---------------------------------------------------------------------------
__global__ __launch_bounds__(256) void transpose4_kernel(
    const float* __restrict__ W0, const float* __restrict__ W1,
    const float* __restrict__ W2, const float* __restrict__ W3,
    ushort_t* __restrict__ qkv_t, ushort_t* __restrict__ o_t)
{
    const int z = blockIdx.z;
    const float* W = (z == 0) ? W0 : (z == 1) ? W1 : (z == 2) ? W2 : W3;
    ushort_t* hi = (z < 3) ? qkv_t + (size_t)z * DIM * DIM : o_t;

    __shared__ float t[64][65];
    const int k0 = blockIdx.x * 64, n0 = blockIdx.y * 64;
    const int lr = threadIdx.x >> 2, lc = (threadIdx.x & 3) * 16;
    #pragma unroll
    for (int j = 0; j < 4; ++j) {
        float4 v = *(const float4*)&W[(size_t)(k0 + lr) * DIM + n0 + lc + j * 4];
        t[lr][lc + j * 4 + 0] = v.x;
        t[lr][lc + j * 4 + 1] = v.y;
        t[lr][lc + j * 4 + 2] = v.z;
        t[lr][lc + j * 4 + 3] = v.w;
    }
    __syncthreads();
    #pragma unroll
    for (int j = 0; j < 16; ++j)
        hi[(size_t)(n0 + lr) * DIM + k0 + lc + j] = f2b(t[lc + j][lr]);
}

__global__ __launch_bounds__(256) void bias_concat_kernel(
    const float* __restrict__ bq, const float* __restrict__ bk,
    const float* __restrict__ bv, float* __restrict__ ball)
{
    int i = blockIdx.x * 256 + threadIdx.x;
    if (i >= 3 * DIM) return;
    float v = (i < DIM) ? bq[i] : (i < 2 * DIM ? bk[i - DIM] : bv[i - 2 * DIM]);
    ball[i] = v;
}

// ---------------------------------------------------------------------------
// bf16 MFMA GEMM: C[M,N] = A[M,K=768](bf16) @ Wt[N,K](bf16)^T + bias
// Exact R1 structure (best measured 103.9 us): global_load_lds dwordx4
// staging into linear [128][32] LDS tiles, single-buffered 2-barrier
// K-loop, 128x128 tile, 4 waves, XCD-swizzled 1-D grid.
// EPI 0: proj 0 (Q) pre-scaled by 1/sqrt(768); q/k -> [B,H,N,HD] bf16;
//        V plane (proj 2) transposed to [B,H,HD,N].  (18 col blocks)
// EPI 1: fp32 [M,768] row-major to d_out.            (6 col blocks)
// ---------------------------------------------------------------------------
template <int EPI>
__global__ __launch_bounds__(256) void mfma_gemm(
    const ushort_t* __restrict__ A, const ushort_t* __restrict__ Bhi,
    const float* __restrict__ bias, void* __restrict__ Cout)
{
    __shared__ ushort_t sA[128 * 32];   // 8 KB, linear pitch 32 (64 B rows)
    __shared__ ushort_t sB[128 * 32];   // 8 KB

    // XCD swizzle: rows fast within the XCD's strip, cols slow
    const int bid = blockIdx.x;
    const int xcd = bid & 7;
    const int o = bid >> 3;
    const int row0 = (xcd * 16 + (o & 15)) * 128;
    const int col0 = (o >> 4) * 128;

    const int tid = threadIdx.x;
    const int lane = tid & 63;
    const int wave = tid >> 6;
    const int wm = (wave & 1) * 64;
    const int wn = (wave >> 1) * 64;
    const int m16 = lane & 15;
    const int quad = lane >> 4;

    // staging geometry: one global_load_lds writes 64 lanes * 16 B = 16 rows
    // of 32 bf16. Wave w owns rows [w*32, w*32+32) via 2 instructions per tile.
    const int srow = lane >> 2;          // row within a 16-row group
    const int schunk = (lane & 3) * 8;   // 16 B chunk within a row (bf16 elems)

    const size_t aoff = (size_t)(row0 + wave * 32 + srow) * DIM + schunk;
    const size_t boff = (size_t)(col0 + wave * 32 + srow) * DIM + schunk;
    ushort_t* lA0 = sA + wave * 1024;    // wave-uniform LDS bases
    ushort_t* lA1 = lA0 + 512;
    ushort_t* lB0 = sB + wave * 1024;
    ushort_t* lB1 = lB0 + 512;

    floatx4 acc[4][4];
    #pragma unroll
    for (int i = 0; i < 4; ++i)
        #pragma unroll
        for (int j = 0; j < 4; ++j)
            acc[i][j] = (floatx4){0.f, 0.f, 0.f, 0.f};

    for (int k0 = 0; k0 < DIM; k0 += 32) {
        __syncthreads();   // all waves done reading previous tile
        gl2lds16(A + aoff + k0, lA0);
        gl2lds16(A + aoff + (size_t)16 * DIM + k0, lA1);
        gl2lds16(Bhi + boff + k0, lB0);
        gl2lds16(Bhi + boff + (size_t)16 * DIM + k0, lB1);
        __syncthreads();   // compiler drains vmcnt(0) before this barrier

        short8 af[4], bh[4];
        #pragma unroll
        for (int i = 0; i < 4; ++i) {
            af[i] = *(const short8*)&sA[(wm + i * 16 + m16) * 32 + quad * 8];
            bh[i] = *(const short8*)&sB[(wn + i * 16 + m16) * 32 + quad * 8];
        }
        #pragma unroll
        for (int i = 0; i < 4; ++i)
            #pragma unroll
            for (int j = 0; j < 4; ++j)
                acc[i][j] = __builtin_amdgcn_mfma_f32_16x16x32_bf16(af[i], bh[j], acc[i][j], 0, 0, 0);
    }

    if (EPI == 0) {
        const int proj = col0 / DIM;      // uniform per block (128 | 768)
        const int rem0 = col0 % DIM;
        const float sc = (proj == 0) ? kScale : 1.0f;   // pre-scale Q
        ushort_t* C = (ushort_t*)Cout + (size_t)proj * MATE;
        #pragma unroll
        for (int j = 0; j < 4; ++j) {
            const int coff = wn + j * 16 + m16;
            const int cc = rem0 + coff;
            const int h = cc >> 6, dd = cc & 63;
            const float bs = bias[col0 + coff];
            #pragma unroll
            for (int i = 0; i < 4; ++i)
                #pragma unroll
                for (int r = 0; r < 4; ++r) {
                    const int m = row0 + wm + i * 16 + quad * 4 + r;
                    const int bb = m >> 10, nn = m & 1023;
                    if (proj < 2) {
                        C[(((size_t)(bb * NH + h) * SEQ + nn) << 6) + dd] =
                            f2b((acc[i][j][r] + bs) * sc);
                    } else {
                        C[((((size_t)(bb * NH + h) << 6) + dd) << 10) + nn] =
                            f2b(acc[i][j][r] + bs);
                    }
                }
        }
    } else {
        float* C = (float*)Cout;
        #pragma unroll
        for (int j = 0; j < 4; ++j) {
            const int coff = wn + j * 16 + m16;
            const float bs = bias[col0 + coff];
            #pragma unroll
            for (int i = 0; i < 4; ++i)
                #pragma unroll
                for (int r = 0; r < 4; ++r) {
                    const int m = row0 + wm + i * 16 + quad * 4 + r;
                    C[(size_t)m * DIM + col0 + coff] = acc[i][j][r] + bs;
                }
        }
    }
}

// ---------------------------------------------------------------------------
// MFMA flash attention, bf16 in/out, fp32 accumulate.
// NEW (this round): NO K/V LDS staging, NO K-loop barriers. K+V per head is
// 256 KB = L2-resident (each XCD's 8 q-tiles of a head re-read it; m169:
// staging L2-fit data was pure overhead). K/V fragments load directly
// global->VGPR (bit-exact remap of the old LDS-staged addresses). Ps is
// wave-private (rows wq..wq+31), so the 4 waves run fully independently;
// latency hides via TLP instead of barrier-lockstep. setprio(1) wraps the
// MFMA clusters (m191: helps when waves are at different phases).
// LDS = 128*72*2 = 18.4 KB (Ps only; reused for O at the end).
// ---------------------------------------------------------------------------
#define APK 72   // LDS row pitch (bf16): 144 B
__global__ __launch_bounds__(256) void attn_kernel(
    const ushort_t* __restrict__ Q, const ushort_t* __restrict__ K,
    const ushort_t* __restrict__ Vt, ushort_t* __restrict__ Aout)
{
    __shared__ ushort_t Ps[128 * APK];   // P tile; reused for O at the end

    const int bid = blockIdx.x;          // 1536 blocks
    const int xcd = bid & 7;
    const int o = bid >> 3;              // 0..191
    const int bh = xcd * 24 + (o >> 3);  // 24 heads per XCD
    const int q0 = (o & 7) * 128;        // q-tiles fast -> K/V L2 reuse

    const int tid = threadIdx.x;
    const int lane = tid & 63;
    const int wave = tid >> 6;
    const int wq = wave * 32;
    const int m16 = lane & 15;
    const int quad = lane >> 4;
    const size_t base  = (size_t)bh * SEQ * HD;   // Q,K: [N][HD]
    const size_t baseT = (size_t)bh * HD * SEQ;   // Vt:  [HD][N]

    // Q A-fragments: 2 q-frags x 2 k-chunks, held in regs whole kernel
    short8 qf[2][2];
    #pragma unroll
    for (int f = 0; f < 2; ++f)
        #pragma unroll
        for (int kc = 0; kc < 2; ++kc)
            qf[f][kc] = *(const short8*)&Q[base +
                (size_t)(q0 + wq + f * 16 + m16) * HD + kc * 32 + quad * 8];

    floatx4 oacc[2][4];
    float lacc[2][4];
    #pragma unroll
    for (int f = 0; f < 2; ++f) {
        #pragma unroll
        for (int dt = 0; dt < 4; ++dt) oacc[f][dt] = (floatx4){0.f, 0.f, 0.f, 0.f};
        #pragma unroll
        for (int r = 0; r < 4; ++r) lacc[f][r] = 0.0f;
    }

    for (int kt = 0; kt < SEQ / 64; ++kt) {
        const int k1 = kt * 64;

        // S = Q K^T : K fragments straight from L1/L2 (bit-exact remap of
        // the old Ks[(t*16+m16)*APK + kc*32+quad*8] contents)
        short8 kf[2][4];
        #pragma unroll
        for (int kc = 0; kc < 2; ++kc)
            #pragma unroll
            for (int t = 0; t < 4; ++t)
                kf[kc][t] = *(const short8*)&K[base +
                    (size_t)(k1 + t * 16 + m16) * HD + kc * 32 + quad * 8];
        floatx4 sacc[2][4];
        #pragma unroll
        for (int f = 0; f < 2; ++f)
            #pragma unroll
            for (int t = 0; t < 4; ++t)
                sacc[f][t] = (floatx4){0.f, 0.f, 0.f, 0.f};
        __builtin_amdgcn_s_setprio(1);
        #pragma unroll
        for (int kc = 0; kc < 2; ++kc)
            #pragma unroll
            for (int f = 0; f < 2; ++f)
                #pragma unroll
                for (int t = 0; t < 4; ++t)
                    sacc[f][t] = __builtin_amdgcn_mfma_f32_16x16x32_bf16(
                        qf[f][kc], kf[kc][t], sacc[f][t], 0, 0, 0);
        __builtin_amdgcn_s_setprio(0);

        // max-free softmax: p = exp(s); per-lane partial row sums
        #pragma unroll
        for (int f = 0; f < 2; ++f)
            #pragma unroll
            for (int r = 0; r < 4; ++r) {
                float rs = 0.0f;
                #pragma unroll
                for (int t = 0; t < 4; ++t) {
                    ushort_t u = f2b(__expf(sacc[f][t][r]));
                    Ps[(wq + f * 16 + quad * 4 + r) * APK + t * 16 + m16] = u;
                    rs += b2f(u);   // sum ROUNDED p -> exact normalization
                }
                lacc[f][r] += rs;
            }

        // O += P V : V fragments straight from L1/L2 (bit-exact remap of
        // the old Vs[(dt*16+m16)*APK + kc*32+quad*8] contents)
        short8 vf[2][4];
        #pragma unroll
        for (int kc = 0; kc < 2; ++kc)
            #pragma unroll
            for (int dt = 0; dt < 4; ++dt)
                vf[kc][dt] = *(const short8*)&Vt[baseT +
                    (size_t)(dt * 16 + m16) * SEQ + k1 + kc * 32 + quad * 8];
        __builtin_amdgcn_s_setprio(1);
        #pragma unroll
        for (int f = 0; f < 2; ++f) {
            #pragma unroll
            for (int kc = 0; kc < 2; ++kc) {
                short8 pf = *(const short8*)&Ps[(wq + f * 16 + m16) * APK + kc * 32 + quad * 8];
                #pragma unroll
                for (int dt = 0; dt < 4; ++dt)
                    oacc[f][dt] = __builtin_amdgcn_mfma_f32_16x16x32_bf16(
                        pf, vf[kc][dt], oacc[f][dt], 0, 0, 0);
            }
        }
        __builtin_amdgcn_s_setprio(0);
    }

    // one cross-lane reduction for l, then normalize
    float inv[2][4];
    #pragma unroll
    for (int f = 0; f < 2; ++f)
        #pragma unroll
        for (int r = 0; r < 4; ++r) {
            float l = lacc[f][r];
            l += __shfl_xor(l, 1);
            l += __shfl_xor(l, 2);
            l += __shfl_xor(l, 4);
            l += __shfl_xor(l, 8);
            inv[f][r] = 1.0f / l;
        }

    // stage O (bf16) into Ps [q][d] (wave-private rows), then coalesced store
    #pragma unroll
    for (int f = 0; f < 2; ++f)
        #pragma unroll
        for (int dt = 0; dt < 4; ++dt)
            #pragma unroll
            for (int r = 0; r < 4; ++r)
                Ps[(wq + f * 16 + quad * 4 + r) * APK + dt * 16 + m16] =
                    f2b(oacc[f][dt][r] * inv[f][r]);
    __syncthreads();

    const int b = bh / NH, h = bh % NH;
    const int orow = tid >> 1;             // 0..127
    const int oc = (tid & 1) * 32;         // bf16 offset
    const size_t row = (size_t)b * SEQ + q0 + orow;
    #pragma unroll
    for (int j = 0; j < 4; ++j) {
        uint4 ov = *(const uint4*)&Ps[orow * APK + oc + j * 8];
        *(uint4*)&Aout[row * DIM + h * HD + oc + j * 8] = ov;
    }
}

extern "C" void kernel_launch(void* const* d_in, const int* in_sizes, int n_in,
                              void* d_out, int out_size, void* d_ws, size_t ws_size,
                              hipStream_t stream)
{
    const float* X  = (const float*)d_in[0];
    const float* Wq = (const float*)d_in[1];
    const float* bq = (const float*)d_in[2];
    const float* Wk = (const float*)d_in[3];
    const float* bk = (const float*)d_in[4];
    const float* Wv = (const float*)d_in[5];
    const float* bv = (const float*)d_in[6];
    const float* Wo = (const float*)d_in[7];
    const float* bo = (const float*)d_in[8];

    ushort_t* qkv  = (ushort_t*)d_ws;                 // q,k [B,H,N,HD]; v [B,H,HD,N]
    ushort_t* abuf = qkv + 3 * MATE;
    ushort_t* xbf  = abuf + MATE;
    ushort_t* wqkv_t = xbf + MATE;                    // 2304*768 bf16
    ushort_t* wo_t   = wqkv_t + (size_t)3 * DIM * DIM;
    float* ball = (float*)(wo_t + (size_t)DIM * DIM); // 2304 floats

    cvt_bf16_kernel<<<(int)(MATE / 4 + 255) / 256, 256, 0, stream>>>(X, xbf, (int)(MATE / 4));
    transpose4_kernel<<<dim3(DIM / 64, DIM / 64, 4), 256, 0, stream>>>(
        Wq, Wk, Wv, Wo, wqkv_t, wo_t);
    bias_concat_kernel<<<(3 * DIM + 255) / 256, 256, 0, stream>>>(bq, bk, bv, ball);

    // QKV projection: 18 col-blocks x 128 row-blocks, XCD-swizzled 1-D
    mfma_gemm<0><<<dim3(18 * 128), 256, 0, stream>>>(xbf, wqkv_t, ball, qkv);

    attn_kernel<<<dim3((SEQ / 128) * BATCH * NH), 256, 0, stream>>>(
        qkv, qkv + MATE, qkv + 2 * MATE, abuf);

    // out projection: 6 col-blocks x 128 row-blocks, XCD-swizzled 1-D
    mfma_gemm<1><<<dim3(6 * 128), 256, 0, stream>>>(abuf, wo_t, bo, d_out);
}

// Round 8
// 351.930 us; speedup vs baseline: 1.2026x; 1.2026x over previous
//
#include <hip/hip_runtime.h>
#include <hip/hip_bf16.h>
#include <math.h>

#define DIM 768
#define NH 12
#define HD 64
#define BATCH 16
#define SEQ 1024
#define M_TOTAL (BATCH * SEQ)   // 16384
#define MATE ((size_t)M_TOTAL * DIM)  // elements per activation plane

typedef unsigned short ushort_t;
typedef __attribute__((ext_vector_type(8))) short short8;
typedef __attribute__((ext_vector_type(4))) float floatx4;

__device__ __constant__ float kScale = 0.03608439182435161f; // 1/sqrt(768)

__device__ inline ushort_t f2b(float x) {
    __hip_bfloat16 h = __float2bfloat16(x);
    return __builtin_bit_cast(ushort_t, h);
}
__device__ inline float b2f_u32(unsigned int bits16) {
    union { unsigned int i; float f; } c;
    c.i = bits16 << 16;
    return c.f;
}
__device__ inline float b2f(ushort_t u) { return b2f_u32((unsigned int)u); }

// async global->LDS, 16 B per lane; LDS dest is wave-uniform base + lane*16
__device__ __forceinline__ void gl2lds16(const ushort_t* g, ushort_t* l) {
    __builtin_amdgcn_global_load_lds(
        (__attribute__((address_space(1))) void*)g,
        (__attribute__((address_space(3))) void*)l, 16, 0, 0);
}

// ---------------------------------------------------------------------------
// fp32 -> bf16 plane
// ---------------------------------------------------------------------------
__global__ __launch_bounds__(256) void cvt_bf16_kernel(
    const float* __restrict__ X, ushort_t* __restrict__ Y, int n4)
{
    int i = blockIdx.x * 256 + threadIdx.x;
    if (i >= n4) return;
    float4 v = ((const float4*)X)[i];
    ushort4 o;
    o.x = f2b(v.x); o.y = f2b(v.y); o.z = f2b(v.z); o.w = f2b(v.w);
    ((ushort4*)Y)[i] = o;
}

// ---------------------------------------------------------------------------
// All 4 weights: W[k][n] fp32 -> transposed bf16 plane Wt[n][k].
// blockIdx.z selects the matrix (0=Wq,1=Wk,2=Wv,3=Wo).
// ---------------------------------------------------------------------------
__global__ __launch_bounds__(256) void transpose4_kernel(
    const float* __restrict__ W0, const float* __restrict__ W1,
    const float* __restrict__ W2, const float* __restrict__ W3,
    ushort_t* __restrict__ qkv_t, ushort_t* __restrict__ o_t)
{
    const int z = blockIdx.z;
    const float* W = (z == 0) ? W0 : (z == 1) ? W1 : (z == 2) ? W2 : W3;
    ushort_t* hi = (z < 3) ? qkv_t + (size_t)z * DIM * DIM : o_t;

    __shared__ float t[64][65];
    const int k0 = blockIdx.x * 64, n0 = blockIdx.y * 64;
    const int lr = threadIdx.x >> 2, lc = (threadIdx.x & 3) * 16;
    #pragma unroll
    for (int j = 0; j < 4; ++j) {
        float4 v = *(const float4*)&W[(size_t)(k0 + lr) * DIM + n0 + lc + j * 4];
        t[lr][lc + j * 4 + 0] = v.x;
        t[lr][lc + j * 4 + 1] = v.y;
        t[lr][lc + j * 4 + 2] = v.z;
        t[lr][lc + j * 4 + 3] = v.w;
    }
    __syncthreads();
    #pragma unroll
    for (int j = 0; j < 16; ++j)
        hi[(size_t)(n0 + lr) * DIM + k0 + lc + j] = f2b(t[lc + j][lr]);
}

__global__ __launch_bounds__(256) void bias_concat_kernel(
    const float* __restrict__ bq, const float* __restrict__ bk,
    const float* __restrict__ bv, float* __restrict__ ball)
{
    int i = blockIdx.x * 256 + threadIdx.x;
    if (i >= 3 * DIM) return;
    float v = (i < DIM) ? bq[i] : (i < 2 * DIM ? bk[i - DIM] : bv[i - 2 * DIM]);
    ball[i] = v;
}

// ---------------------------------------------------------------------------
// bf16 MFMA GEMM: C[M,N] = A[M,K=768](bf16) @ Wt[N,K](bf16)^T + bias
// Exact R1 structure (best measured 103.9 us).
// ---------------------------------------------------------------------------
template <int EPI>
__global__ __launch_bounds__(256) void mfma_gemm(
    const ushort_t* __restrict__ A, const ushort_t* __restrict__ Bhi,
    const float* __restrict__ bias, void* __restrict__ Cout)
{
    __shared__ ushort_t sA[128 * 32];   // 8 KB, linear pitch 32 (64 B rows)
    __shared__ ushort_t sB[128 * 32];   // 8 KB

    // XCD swizzle: rows fast within the XCD's strip, cols slow
    const int bid = blockIdx.x;
    const int xcd = bid & 7;
    const int o = bid >> 3;
    const int row0 = (xcd * 16 + (o & 15)) * 128;
    const int col0 = (o >> 4) * 128;

    const int tid = threadIdx.x;
    const int lane = tid & 63;
    const int wave = tid >> 6;
    const int wm = (wave & 1) * 64;
    const int wn = (wave >> 1) * 64;
    const int m16 = lane & 15;
    const int quad = lane >> 4;

    const int srow = lane >> 2;          // row within a 16-row group
    const int schunk = (lane & 3) * 8;   // 16 B chunk within a row (bf16 elems)

    const size_t aoff = (size_t)(row0 + wave * 32 + srow) * DIM + schunk;
    const size_t boff = (size_t)(col0 + wave * 32 + srow) * DIM + schunk;
    ushort_t* lA0 = sA + wave * 1024;    // wave-uniform LDS bases
    ushort_t* lA1 = lA0 + 512;
    ushort_t* lB0 = sB + wave * 1024;
    ushort_t* lB1 = lB0 + 512;

    floatx4 acc[4][4];
    #pragma unroll
    for (int i = 0; i < 4; ++i)
        #pragma unroll
        for (int j = 0; j < 4; ++j)
            acc[i][j] = (floatx4){0.f, 0.f, 0.f, 0.f};

    for (int k0 = 0; k0 < DIM; k0 += 32) {
        __syncthreads();   // all waves done reading previous tile
        gl2lds16(A + aoff + k0, lA0);
        gl2lds16(A + aoff + (size_t)16 * DIM + k0, lA1);
        gl2lds16(Bhi + boff + k0, lB0);
        gl2lds16(Bhi + boff + (size_t)16 * DIM + k0, lB1);
        __syncthreads();   // compiler drains vmcnt(0) before this barrier

        short8 af[4], bh[4];
        #pragma unroll
        for (int i = 0; i < 4; ++i) {
            af[i] = *(const short8*)&sA[(wm + i * 16 + m16) * 32 + quad * 8];
            bh[i] = *(const short8*)&sB[(wn + i * 16 + m16) * 32 + quad * 8];
        }
        #pragma unroll
        for (int i = 0; i < 4; ++i)
            #pragma unroll
            for (int j = 0; j < 4; ++j)
                acc[i][j] = __builtin_amdgcn_mfma_f32_16x16x32_bf16(af[i], bh[j], acc[i][j], 0, 0, 0);
    }

    if (EPI == 0) {
        const int proj = col0 / DIM;      // uniform per block (128 | 768)
        const int rem0 = col0 % DIM;
        const float sc = (proj == 0) ? kScale : 1.0f;   // pre-scale Q
        ushort_t* C = (ushort_t*)Cout + (size_t)proj * MATE;
        #pragma unroll
        for (int j = 0; j < 4; ++j) {
            const int coff = wn + j * 16 + m16;
            const int cc = rem0 + coff;
            const int h = cc >> 6, dd = cc & 63;
            const float bs = bias[col0 + coff];
            #pragma unroll
            for (int i = 0; i < 4; ++i)
                #pragma unroll
                for (int r = 0; r < 4; ++r) {
                    const int m = row0 + wm + i * 16 + quad * 4 + r;
                    const int bb = m >> 10, nn = m & 1023;
                    if (proj < 2) {
                        C[(((size_t)(bb * NH + h) * SEQ + nn) << 6) + dd] =
                            f2b((acc[i][j][r] + bs) * sc);
                    } else {
                        C[((((size_t)(bb * NH + h) << 6) + dd) << 10) + nn] =
                            f2b(acc[i][j][r] + bs);
                    }
                }
        }
    } else {
        float* C = (float*)Cout;
        #pragma unroll
        for (int j = 0; j < 4; ++j) {
            const int coff = wn + j * 16 + m16;
            const float bs = bias[col0 + coff];
            #pragma unroll
            for (int i = 0; i < 4; ++i)
                #pragma unroll
                for (int r = 0; r < 4; ++r) {
                    const int m = row0 + wm + i * 16 + quad * 4 + r;
                    C[(size_t)m * DIM + col0 + coff] = acc[i][j][r] + bs;
                }
        }
    }
}

// ---------------------------------------------------------------------------
// MFMA flash attention, bf16 in/out, fp32 accumulate.
// NEW (this round): T3-minimum pipeline on the staged structure --
// double-buffered K/V tiles staged via global_load_lds (width 16), ONE
// barrier per K-tile (iter kt stages tile kt+1 into buf^1 async, computes
// tile kt; top-of-loop vmcnt(0)+barrier is ~free after a full iteration of
// compute). Reads of buf^1 in iter kt-1 complete before that wave's PV
// (data dep) hence before barrier(kt); writes to buf^1 issue after it.
// K/V/Ps use pitch 64 (128 B rows, no pad -- linear dest required by
// global_load_lds) with the XOR slot involution (phys 16B-slot =
// logical ^ (row&7)): global SOURCE pre-swizzled, ds_read swizzled
// (rule 21; verified R2/R4, 0 conflicts). Bit-identical numerics.
// LDS = 2*2*8 KB (K/V dbuf) + 16 KB (Ps) = 48 KB -> 3 blocks/CU.
// ---------------------------------------------------------------------------
#define LP 64   // LDS row pitch (ushorts) = 128 B
__global__ __launch_bounds__(256) void attn_kernel(
    const ushort_t* __restrict__ Q, const ushort_t* __restrict__ K,
    const ushort_t* __restrict__ Vt, ushort_t* __restrict__ Aout)
{
    __shared__ ushort_t Ks[2][64 * LP];
    __shared__ ushort_t Vs[2][64 * LP];
    __shared__ ushort_t Ps[128 * LP];    // P tile; reused for O at the end

    const int bid = blockIdx.x;          // 1536 blocks
    const int xcd = bid & 7;
    const int o = bid >> 3;              // 0..191
    const int bh = xcd * 24 + (o >> 3);  // 24 heads per XCD
    const int q0 = (o & 7) * 128;        // q-tiles fast -> K/V L2 reuse

    const int tid = threadIdx.x;
    const int lane = tid & 63;
    const int wave = tid >> 6;
    const int wq = wave * 32;
    const int m16 = lane & 15;
    const int quad = lane >> 4;
    const size_t base  = (size_t)bh * SEQ * HD;   // Q,K: [N][HD]
    const size_t baseT = (size_t)bh * HD * SEQ;   // Vt:  [HD][N]

    // staging geometry: tile = 64 rows x 8 slots (16 B) = 512 slots.
    // wave covers slots [wave*128, +128) via 2 gl2lds of 64 slots each.
    // linear LDS dest; SOURCE pre-swizzled: slot q -> row q>>3,
    // global col-slot (q&7)^(row&7).
    int srow[2], scol[2], ldso[2];
    #pragma unroll
    for (int j = 0; j < 2; ++j) {
        const int q = wave * 128 + j * 64 + lane;
        srow[j] = q >> 3;
        scol[j] = ((q & 7) ^ ((q >> 3) & 7)) * 8;     // ushorts
        ldso[j] = (wave * 128 + j * 64) * 8;          // wave-uniform
    }

    // Q A-fragments: 2 q-frags x 2 k-chunks, held in regs whole kernel
    short8 qf[2][2];
    #pragma unroll
    for (int f = 0; f < 2; ++f)
        #pragma unroll
        for (int kc = 0; kc < 2; ++kc)
            qf[f][kc] = *(const short8*)&Q[base +
                (size_t)(q0 + wq + f * 16 + m16) * HD + kc * 32 + quad * 8];

    floatx4 oacc[2][4];
    float lacc[2][4];
    #pragma unroll
    for (int f = 0; f < 2; ++f) {
        #pragma unroll
        for (int dt = 0; dt < 4; ++dt) oacc[f][dt] = (floatx4){0.f, 0.f, 0.f, 0.f};
        #pragma unroll
        for (int r = 0; r < 4; ++r) lacc[f][r] = 0.0f;
    }

    // stage tile 0 into buf 0
    #pragma unroll
    for (int j = 0; j < 2; ++j) {
        gl2lds16(K + base + (size_t)srow[j] * HD + scol[j], &Ks[0][ldso[j]]);
        gl2lds16(Vt + baseT + (size_t)srow[j] * SEQ + scol[j], &Vs[0][ldso[j]]);
    }

    for (int kt = 0; kt < SEQ / 64; ++kt) {
        const int cb = kt & 1;
        asm volatile("s_waitcnt vmcnt(0)" ::: "memory");  // my stages landed
        __syncthreads();                                  // everyone's landed
        if (kt + 1 < SEQ / 64) {       // stage next tile into other buffer
            const int k1 = (kt + 1) * 64;
            #pragma unroll
            for (int j = 0; j < 2; ++j) {
                gl2lds16(K + base + (size_t)(k1 + srow[j]) * HD + scol[j],
                         &Ks[cb ^ 1][ldso[j]]);
                gl2lds16(Vt + baseT + (size_t)srow[j] * SEQ + k1 + scol[j],
                         &Vs[cb ^ 1][ldso[j]]);
            }
        }

        // S = Q K^T : K frags read once, reused for both q-frags
        short8 kf[2][4];
        #pragma unroll
        for (int kc = 0; kc < 2; ++kc)
            #pragma unroll
            for (int t = 0; t < 4; ++t)
                kf[kc][t] = *(const short8*)&Ks[cb][(t * 16 + m16) * LP +
                    (((kc * 4 + quad) ^ (m16 & 7)) * 8)];
        floatx4 sacc[2][4];
        #pragma unroll
        for (int f = 0; f < 2; ++f)
            #pragma unroll
            for (int t = 0; t < 4; ++t)
                sacc[f][t] = (floatx4){0.f, 0.f, 0.f, 0.f};
        #pragma unroll
        for (int kc = 0; kc < 2; ++kc)
            #pragma unroll
            for (int f = 0; f < 2; ++f)
                #pragma unroll
                for (int t = 0; t < 4; ++t)
                    sacc[f][t] = __builtin_amdgcn_mfma_f32_16x16x32_bf16(
                        qf[f][kc], kf[kc][t], sacc[f][t], 0, 0, 0);

        // max-free softmax: p = exp(s); per-lane partial row sums
        #pragma unroll
        for (int f = 0; f < 2; ++f)
            #pragma unroll
            for (int r = 0; r < 4; ++r) {
                float rs = 0.0f;
                const int prow = wq + f * 16 + quad * 4 + r;
                #pragma unroll
                for (int t = 0; t < 4; ++t) {
                    ushort_t u = f2b(__expf(sacc[f][t][r]));
                    const int pcol = t * 16 + m16;
                    Ps[prow * LP + (((pcol >> 3) ^ (prow & 7)) << 3) + (pcol & 7)] = u;
                    rs += b2f(u);   // sum ROUNDED p -> exact normalization
                }
                lacc[f][r] += rs;
            }

        // O += P V
        short8 vf[2][4];
        #pragma unroll
        for (int kc = 0; kc < 2; ++kc)
            #pragma unroll
            for (int dt = 0; dt < 4; ++dt)
                vf[kc][dt] = *(const short8*)&Vs[cb][(dt * 16 + m16) * LP +
                    (((kc * 4 + quad) ^ (m16 & 7)) * 8)];
        #pragma unroll
        for (int f = 0; f < 2; ++f) {
            const int prow = wq + f * 16 + m16;
            #pragma unroll
            for (int kc = 0; kc < 2; ++kc) {
                short8 pf = *(const short8*)&Ps[prow * LP +
                    (((kc * 4 + quad) ^ (m16 & 7)) * 8)];
                #pragma unroll
                for (int dt = 0; dt < 4; ++dt)
                    oacc[f][dt] = __builtin_amdgcn_mfma_f32_16x16x32_bf16(
                        pf, vf[kc][dt], oacc[f][dt], 0, 0, 0);
            }
        }
    }

    // one cross-lane reduction for l, then normalize
    float inv[2][4];
    #pragma unroll
    for (int f = 0; f < 2; ++f)
        #pragma unroll
        for (int r = 0; r < 4; ++r) {
            float l = lacc[f][r];
            l += __shfl_xor(l, 1);
            l += __shfl_xor(l, 2);
            l += __shfl_xor(l, 4);
            l += __shfl_xor(l, 8);
            inv[f][r] = 1.0f / l;
        }

    // stage O (bf16) into Ps [q][d] (wave-private rows), then coalesced store
    #pragma unroll
    for (int f = 0; f < 2; ++f)
        #pragma unroll
        for (int dt = 0; dt < 4; ++dt)
            #pragma unroll
            for (int r = 0; r < 4; ++r) {
                const int prow = wq + f * 16 + quad * 4 + r;
                const int pcol = dt * 16 + m16;
                Ps[prow * LP + (((pcol >> 3) ^ (prow & 7)) << 3) + (pcol & 7)] =
                    f2b(oacc[f][dt][r] * inv[f][r]);
            }
    __syncthreads();

    const int b = bh / NH, h = bh % NH;
    const int orow = tid >> 1;             // 0..127
    const int oc = (tid & 1) * 32;         // bf16 offset
    const size_t row = (size_t)b * SEQ + q0 + orow;
    #pragma unroll
    for (int j = 0; j < 4; ++j) {
        const int slot = (oc >> 3) + j;
        uint4 ov = *(const uint4*)&Ps[orow * LP + ((slot ^ (orow & 7)) << 3)];
        *(uint4*)&Aout[row * DIM + h * HD + oc + j * 8] = ov;
    }
}

extern "C" void kernel_launch(void* const* d_in, const int* in_sizes, int n_in,
                              void* d_out, int out_size, void* d_ws, size_t ws_size,
                              hipStream_t stream)
{
    const float* X  = (const float*)d_in[0];
    const float* Wq = (const float*)d_in[1];
    const float* bq = (const float*)d_in[2];
    const float* Wk = (const float*)d_in[3];
    const float* bk = (const float*)d_in[4];
    const float* Wv = (const float*)d_in[5];
    const float* bv = (const float*)d_in[6];
    const float* Wo = (const float*)d_in[7];
    const float* bo = (const float*)d_in[8];

    ushort_t* qkv  = (ushort_t*)d_ws;                 // q,k [B,H,N,HD]; v [B,H,HD,N]
    ushort_t* abuf = qkv + 3 * MATE;
    ushort_t* xbf  = abuf + MATE;
    ushort_t* wqkv_t = xbf + MATE;                    // 2304*768 bf16
    ushort_t* wo_t   = wqkv_t + (size_t)3 * DIM * DIM;
    float* ball = (float*)(wo_t + (size_t)DIM * DIM); // 2304 floats

    cvt_bf16_kernel<<<(int)(MATE / 4 + 255) / 256, 256, 0, stream>>>(X, xbf, (int)(MATE / 4));
    transpose4_kernel<<<dim3(DIM / 64, DIM / 64, 4), 256, 0, stream>>>(
        Wq, Wk, Wv, Wo, wqkv_t, wo_t);
    bias_concat_kernel<<<(3 * DIM + 255) / 256, 256, 0, stream>>>(bq, bk, bv, ball);

    // QKV projection: 18 col-blocks x 128 row-blocks, XCD-swizzled 1-D
    mfma_gemm<0><<<dim3(18 * 128), 256, 0, stream>>>(xbf, wqkv_t, ball, qkv);

    attn_kernel<<<dim3((SEQ / 128) * BATCH * NH), 256, 0, stream>>>(
        qkv, qkv + MATE, qkv + 2 * MATE, abuf);

    // out projection: 6 col-blocks x 128 row-blocks, XCD-swizzled 1-D
    mfma_gemm<1><<<dim3(6 * 128), 256, 0, stream>>>(abuf, wo_t, bo, d_out);
}

// Round 9
// 345.532 us; speedup vs baseline: 1.2249x; 1.0185x over previous
//
#include <hip/hip_runtime.h>
#include <hip/hip_bf16.h>
#include <math.h>

#define DIM 768
#define NH 12
#define HD 64
#define BATCH 16
#define SEQ 1024
#define M_TOTAL (BATCH * SEQ)   // 16384
#define MATE ((size_t)M_TOTAL * DIM)  // elements per activation plane

typedef unsigned short ushort_t;
typedef __attribute__((ext_vector_type(8))) short short8;
typedef __attribute__((ext_vector_type(4))) float floatx4;

__device__ __constant__ float kScale = 0.03608439182435161f; // 1/sqrt(768)

__device__ inline ushort_t f2b(float x) {
    __hip_bfloat16 h = __float2bfloat16(x);
    return __builtin_bit_cast(ushort_t, h);
}
__device__ inline float b2f_u32(unsigned int bits16) {
    union { unsigned int i; float f; } c;
    c.i = bits16 << 16;
    return c.f;
}
__device__ inline float b2f(ushort_t u) { return b2f_u32((unsigned int)u); }

// async global->LDS, 16 B per lane; LDS dest is wave-uniform base + lane*16
__device__ __forceinline__ void gl2lds16(const ushort_t* g, ushort_t* l) {
    __builtin_amdgcn_global_load_lds(
        (__attribute__((address_space(1))) void*)g,
        (__attribute__((address_space(3))) void*)l, 16, 0, 0);
}

// ---------------------------------------------------------------------------
// fp32 -> bf16 plane
// ---------------------------------------------------------------------------
__global__ __launch_bounds__(256) void cvt_bf16_kernel(
    const float* __restrict__ X, ushort_t* __restrict__ Y, int n4)
{
    int i = blockIdx.x * 256 + threadIdx.x;
    if (i >= n4) return;
    float4 v = ((const float4*)X)[i];
    ushort4 o;
    o.x = f2b(v.x); o.y = f2b(v.y); o.z = f2b(v.z); o.w = f2b(v.w);
    ((ushort4*)Y)[i] = o;
}

// ---------------------------------------------------------------------------
// All 4 weights: W[k][n] fp32 -> transposed bf16 plane Wt[n][k].
// blockIdx.z selects the matrix (0=Wq,1=Wk,2=Wv,3=Wo).
// ---------------------------------------------------------------------------
__global__ __launch_bounds__(256) void transpose4_kernel(
    const float* __restrict__ W0, const float* __restrict__ W1,
    const float* __restrict__ W2, const float* __restrict__ W3,
    ushort_t* __restrict__ qkv_t, ushort_t* __restrict__ o_t)
{
    const int z = blockIdx.z;
    const float* W = (z == 0) ? W0 : (z == 1) ? W1 : (z == 2) ? W2 : W3;
    ushort_t* hi = (z < 3) ? qkv_t + (size_t)z * DIM * DIM : o_t;

    __shared__ float t[64][65];
    const int k0 = blockIdx.x * 64, n0 = blockIdx.y * 64;
    const int lr = threadIdx.x >> 2, lc = (threadIdx.x & 3) * 16;
    #pragma unroll
    for (int j = 0; j < 4; ++j) {
        float4 v = *(const float4*)&W[(size_t)(k0 + lr) * DIM + n0 + lc + j * 4];
        t[lr][lc + j * 4 + 0] = v.x;
        t[lr][lc + j * 4 + 1] = v.y;
        t[lr][lc + j * 4 + 2] = v.z;
        t[lr][lc + j * 4 + 3] = v.w;
    }
    __syncthreads();
    #pragma unroll
    for (int j = 0; j < 16; ++j)
        hi[(size_t)(n0 + lr) * DIM + k0 + lc + j] = f2b(t[lc + j][lr]);
}

__global__ __launch_bounds__(256) void bias_concat_kernel(
    const float* __restrict__ bq, const float* __restrict__ bk,
    const float* __restrict__ bv, float* __restrict__ ball)
{
    int i = blockIdx.x * 256 + threadIdx.x;
    if (i >= 3 * DIM) return;
    float v = (i < DIM) ? bq[i] : (i < 2 * DIM ? bk[i - DIM] : bv[i - 2 * DIM]);
    ball[i] = v;
}

// ---------------------------------------------------------------------------
// bf16 MFMA GEMM: C[M,N] = A[M,K=768](bf16) @ Wt[N,K](bf16)^T + bias
// Exact R1 structure (best measured 103.9 us).
// ---------------------------------------------------------------------------
template <int EPI>
__global__ __launch_bounds__(256) void mfma_gemm(
    const ushort_t* __restrict__ A, const ushort_t* __restrict__ Bhi,
    const float* __restrict__ bias, void* __restrict__ Cout)
{
    __shared__ ushort_t sA[128 * 32];   // 8 KB, linear pitch 32 (64 B rows)
    __shared__ ushort_t sB[128 * 32];   // 8 KB

    // XCD swizzle: rows fast within the XCD's strip, cols slow
    const int bid = blockIdx.x;
    const int xcd = bid & 7;
    const int o = bid >> 3;
    const int row0 = (xcd * 16 + (o & 15)) * 128;
    const int col0 = (o >> 4) * 128;

    const int tid = threadIdx.x;
    const int lane = tid & 63;
    const int wave = tid >> 6;
    const int wm = (wave & 1) * 64;
    const int wn = (wave >> 1) * 64;
    const int m16 = lane & 15;
    const int quad = lane >> 4;

    const int srow = lane >> 2;          // row within a 16-row group
    const int schunk = (lane & 3) * 8;   // 16 B chunk within a row (bf16 elems)

    const size_t aoff = (size_t)(row0 + wave * 32 + srow) * DIM + schunk;
    const size_t boff = (size_t)(col0 + wave * 32 + srow) * DIM + schunk;
    ushort_t* lA0 = sA + wave * 1024;    // wave-uniform LDS bases
    ushort_t* lA1 = lA0 + 512;
    ushort_t* lB0 = sB + wave * 1024;
    ushort_t* lB1 = lB0 + 512;

    floatx4 acc[4][4];
    #pragma unroll
    for (int i = 0; i < 4; ++i)
        #pragma unroll
        for (int j = 0; j < 4; ++j)
            acc[i][j] = (floatx4){0.f, 0.f, 0.f, 0.f};

    for (int k0 = 0; k0 < DIM; k0 += 32) {
        __syncthreads();   // all waves done reading previous tile
        gl2lds16(A + aoff + k0, lA0);
        gl2lds16(A + aoff + (size_t)16 * DIM + k0, lA1);
        gl2lds16(Bhi + boff + k0, lB0);
        gl2lds16(Bhi + boff + (size_t)16 * DIM + k0, lB1);
        __syncthreads();   // compiler drains vmcnt(0) before this barrier

        short8 af[4], bh[4];
        #pragma unroll
        for (int i = 0; i < 4; ++i) {
            af[i] = *(const short8*)&sA[(wm + i * 16 + m16) * 32 + quad * 8];
            bh[i] = *(const short8*)&sB[(wn + i * 16 + m16) * 32 + quad * 8];
        }
        #pragma unroll
        for (int i = 0; i < 4; ++i)
            #pragma unroll
            for (int j = 0; j < 4; ++j)
                acc[i][j] = __builtin_amdgcn_mfma_f32_16x16x32_bf16(af[i], bh[j], acc[i][j], 0, 0, 0);
    }

    if (EPI == 0) {
        const int proj = col0 / DIM;      // uniform per block (128 | 768)
        const int rem0 = col0 % DIM;
        const float sc = (proj == 0) ? kScale : 1.0f;   // pre-scale Q
        ushort_t* C = (ushort_t*)Cout + (size_t)proj * MATE;
        #pragma unroll
        for (int j = 0; j < 4; ++j) {
            const int coff = wn + j * 16 + m16;
            const int cc = rem0 + coff;
            const int h = cc >> 6, dd = cc & 63;
            const float bs = bias[col0 + coff];
            #pragma unroll
            for (int i = 0; i < 4; ++i)
                #pragma unroll
                for (int r = 0; r < 4; ++r) {
                    const int m = row0 + wm + i * 16 + quad * 4 + r;
                    const int bb = m >> 10, nn = m & 1023;
                    if (proj < 2) {
                        C[(((size_t)(bb * NH + h) * SEQ + nn) << 6) + dd] =
                            f2b((acc[i][j][r] + bs) * sc);
                    } else {
                        C[((((size_t)(bb * NH + h) << 6) + dd) << 10) + nn] =
                            f2b(acc[i][j][r] + bs);
                    }
                }
        }
    } else {
        float* C = (float*)Cout;
        #pragma unroll
        for (int j = 0; j < 4; ++j) {
            const int coff = wn + j * 16 + m16;
            const float bs = bias[col0 + coff];
            #pragma unroll
            for (int i = 0; i < 4; ++i)
                #pragma unroll
                for (int r = 0; r < 4; ++r) {
                    const int m = row0 + wm + i * 16 + quad * 4 + r;
                    C[(size_t)m * DIM + col0 + coff] = acc[i][j][r] + bs;
                }
        }
    }
}

// ---------------------------------------------------------------------------
// MFMA flash attention, bf16 in/out, fp32 accumulate. R1 staging skeleton
// (reg-prefetch K/V -> LDS, 2 barriers/tile, APK=72).
// NEW (this round): in-register softmax via SWAPPED QK^T (T12 idea):
//   - sacc = mfma(kf, qf) -> S^T: lane holds P for its OWN query (col=m16),
//     keys quad*4+r per t-subtile.
//   - P packed to bf16-pair u32s in registers (pk); PV A-fragments built
//     with __shfl from the 4 quads of the same m16 column + (quad&2) select
//     (elem j of chunk kc*32+quad*8+j comes from src quad (quad&1)*2+(j>>2),
//     t-subtile kc*2+(quad>>1), reg j&3). NO P LDS round-trip: deletes 32
//     scalar ds_writes + 8 b128 reads + rounded-sum chain per tile.
//   - l via ones-column MFMA: lx[f] = mfma(pf, ones, lx[f]) sums the
//     ROUNDED P exactly on the idle MFMA pipe, and lands l[query] aligned
//     with oacc rows (quad*4+r) -> inv[f][r] = 1/lx[f][r], no shfl reduce.
// Ps LDS buffer kept only for the final O staging/coalesced store.
// ---------------------------------------------------------------------------
#define APK 72   // LDS row pitch (bf16): 144 B
__global__ __launch_bounds__(256) void attn_kernel(
    const ushort_t* __restrict__ Q, const ushort_t* __restrict__ K,
    const ushort_t* __restrict__ Vt, ushort_t* __restrict__ Aout)
{
    __shared__ ushort_t Ks[64 * APK];
    __shared__ ushort_t Vs[64 * APK];
    __shared__ ushort_t Ps[128 * APK];   // O staging only

    const int bid = blockIdx.x;          // 1536 blocks
    const int xcd = bid & 7;
    const int o = bid >> 3;              // 0..191
    const int bh = xcd * 24 + (o >> 3);  // 24 heads per XCD
    const int q0 = (o & 7) * 128;        // q-tiles fast -> K/V L2 reuse

    const int tid = threadIdx.x;
    const int lane = tid & 63;
    const int wave = tid >> 6;
    const int wq = wave * 32;
    const int m16 = lane & 15;
    const int quad = lane >> 4;
    const size_t base  = (size_t)bh * SEQ * HD;   // Q,K: [N][HD]
    const size_t baseT = (size_t)bh * HD * SEQ;   // Vt:  [HD][N]

    const int sr = tid >> 2;            // staging row 0..63
    const int sc = (tid & 3) * 16;      // staging chunk (bf16)

    // shuffle sources for PV fragment assembly (constant per thread)
    const int srcA = (quad & 1) * 32 + m16;   // quad (quad&1)*2, same m16
    const int srcB = srcA + 16;               // quad (quad&1)*2+1
    const bool thi = (quad & 2) != 0;         // t-subtile select: kc*2+(quad>>1)

    // ones B-fragment (bf16 1.0 splat) for the l-column MFMA
    short8 onesv;
    #pragma unroll
    for (int j = 0; j < 8; ++j) onesv[j] = (short)0x3F80;

    // Q fragments (B-operand now): rows = queries via m16, unchanged loads
    short8 qf[2][2];
    #pragma unroll
    for (int f = 0; f < 2; ++f)
        #pragma unroll
        for (int kc = 0; kc < 2; ++kc)
            qf[f][kc] = *(const short8*)&Q[base +
                (size_t)(q0 + wq + f * 16 + m16) * HD + kc * 32 + quad * 8];

    floatx4 oacc[2][4];
    floatx4 lx[2];                       // l accumulator (ones-column)
    #pragma unroll
    for (int f = 0; f < 2; ++f) {
        #pragma unroll
        for (int dt = 0; dt < 4; ++dt) oacc[f][dt] = (floatx4){0.f, 0.f, 0.f, 0.f};
        lx[f] = (floatx4){0.f, 0.f, 0.f, 0.f};
    }

    // prefetch tile 0
    uint4 kv0 = *(const uint4*)&K[base + (size_t)sr * HD + sc];
    uint4 kv1 = *(const uint4*)&K[base + (size_t)sr * HD + sc + 8];
    uint4 vv0 = *(const uint4*)&Vt[baseT + (size_t)sr * SEQ + sc];
    uint4 vv1 = *(const uint4*)&Vt[baseT + (size_t)sr * SEQ + sc + 8];

    for (int kt = 0; kt < SEQ / 64; ++kt) {
        __syncthreads();   // all waves done reading prev Ks/Vs
        *(uint4*)&Ks[sr * APK + sc] = kv0;
        *(uint4*)&Ks[sr * APK + sc + 8] = kv1;
        *(uint4*)&Vs[sr * APK + sc] = vv0;
        *(uint4*)&Vs[sr * APK + sc + 8] = vv1;
        __syncthreads();
        if (kt + 1 < SEQ / 64) {   // prefetch next tile (overlaps compute)
            const int k1 = (kt + 1) * 64;
            kv0 = *(const uint4*)&K[base + (size_t)(k1 + sr) * HD + sc];
            kv1 = *(const uint4*)&K[base + (size_t)(k1 + sr) * HD + sc + 8];
            vv0 = *(const uint4*)&Vt[baseT + (size_t)sr * SEQ + k1 + sc];
            vv1 = *(const uint4*)&Vt[baseT + (size_t)sr * SEQ + k1 + sc + 8];
        }

        // S^T = K Q^T (swapped operands): lane's column = its own query m16
        short8 kf[2][4];
        #pragma unroll
        for (int kc = 0; kc < 2; ++kc)
            #pragma unroll
            for (int t = 0; t < 4; ++t)
                kf[kc][t] = *(const short8*)&Ks[(t * 16 + m16) * APK + kc * 32 + quad * 8];
        floatx4 sacc[2][4];
        #pragma unroll
        for (int f = 0; f < 2; ++f)
            #pragma unroll
            for (int t = 0; t < 4; ++t)
                sacc[f][t] = (floatx4){0.f, 0.f, 0.f, 0.f};
        #pragma unroll
        for (int kc = 0; kc < 2; ++kc)
            #pragma unroll
            for (int f = 0; f < 2; ++f)
                #pragma unroll
                for (int t = 0; t < 4; ++t)
                    sacc[f][t] = __builtin_amdgcn_mfma_f32_16x16x32_bf16(
                        kf[kc][t], qf[f][kc], sacc[f][t], 0, 0, 0);

        // max-free softmax in registers: p = exp(s), packed as bf16 pairs.
        // pk[f][t][w]: keys t*16+quad*4+{2w,2w+1} of query m16.
        unsigned pk[2][4][2];
        #pragma unroll
        for (int f = 0; f < 2; ++f)
            #pragma unroll
            for (int t = 0; t < 4; ++t) {
                ushort2 w0, w1;
                w0.x = f2b(__expf(sacc[f][t][0]));
                w0.y = f2b(__expf(sacc[f][t][1]));
                w1.x = f2b(__expf(sacc[f][t][2]));
                w1.y = f2b(__expf(sacc[f][t][3]));
                pk[f][t][0] = __builtin_bit_cast(unsigned, w0);
                pk[f][t][1] = __builtin_bit_cast(unsigned, w1);
            }

        // V fragments (unchanged)
        short8 vf[2][4];
        #pragma unroll
        for (int kc = 0; kc < 2; ++kc)
            #pragma unroll
            for (int dt = 0; dt < 4; ++dt)
                vf[kc][dt] = *(const short8*)&Vs[(dt * 16 + m16) * APK + kc * 32 + quad * 8];

        // O += P V with in-register P fragments; l += P * ones
        #pragma unroll
        for (int f = 0; f < 2; ++f)
            #pragma unroll
            for (int kc = 0; kc < 2; ++kc) {
                const unsigned aA0 = (unsigned)__shfl((int)pk[f][kc * 2 + 0][0], srcA);
                const unsigned bA0 = (unsigned)__shfl((int)pk[f][kc * 2 + 1][0], srcA);
                const unsigned aA1 = (unsigned)__shfl((int)pk[f][kc * 2 + 0][1], srcA);
                const unsigned bA1 = (unsigned)__shfl((int)pk[f][kc * 2 + 1][1], srcA);
                const unsigned aB0 = (unsigned)__shfl((int)pk[f][kc * 2 + 0][0], srcB);
                const unsigned bB0 = (unsigned)__shfl((int)pk[f][kc * 2 + 1][0], srcB);
                const unsigned aB1 = (unsigned)__shfl((int)pk[f][kc * 2 + 0][1], srcB);
                const unsigned bB1 = (unsigned)__shfl((int)pk[f][kc * 2 + 1][1], srcB);
                uint4 wi;
                wi.x = thi ? bA0 : aA0;
                wi.y = thi ? bA1 : aA1;
                wi.z = thi ? bB0 : aB0;
                wi.w = thi ? bB1 : aB1;
                const short8 pf = __builtin_bit_cast(short8, wi);
                #pragma unroll
                for (int dt = 0; dt < 4; ++dt)
                    oacc[f][dt] = __builtin_amdgcn_mfma_f32_16x16x32_bf16(
                        pf, vf[kc][dt], oacc[f][dt], 0, 0, 0);
                lx[f] = __builtin_amdgcn_mfma_f32_16x16x32_bf16(
                    pf, onesv, lx[f], 0, 0, 0);
            }
    }

    // normalize: lx[f][r] = l for query wq+f*16+quad*4+r (aligned with oacc)
    float inv[2][4];
    #pragma unroll
    for (int f = 0; f < 2; ++f)
        #pragma unroll
        for (int r = 0; r < 4; ++r)
            inv[f][r] = 1.0f / lx[f][r];

    // stage O (bf16) into Ps [q][d] (wave-private rows), then coalesced store
    #pragma unroll
    for (int f = 0; f < 2; ++f)
        #pragma unroll
        for (int dt = 0; dt < 4; ++dt)
            #pragma unroll
            for (int r = 0; r < 4; ++r)
                Ps[(wq + f * 16 + quad * 4 + r) * APK + dt * 16 + m16] =
                    f2b(oacc[f][dt][r] * inv[f][r]);
    __syncthreads();

    const int b = bh / NH, h = bh % NH;
    const int orow = tid >> 1;             // 0..127
    const int oc = (tid & 1) * 32;         // bf16 offset
    const size_t row = (size_t)b * SEQ + q0 + orow;
    #pragma unroll
    for (int j = 0; j < 4; ++j) {
        uint4 ov = *(const uint4*)&Ps[orow * APK + oc + j * 8];
        *(uint4*)&Aout[row * DIM + h * HD + oc + j * 8] = ov;
    }
}

extern "C" void kernel_launch(void* const* d_in, const int* in_sizes, int n_in,
                              void* d_out, int out_size, void* d_ws, size_t ws_size,
                              hipStream_t stream)
{
    const float* X  = (const float*)d_in[0];
    const float* Wq = (const float*)d_in[1];
    const float* bq = (const float*)d_in[2];
    const float* Wk = (const float*)d_in[3];
    const float* bk = (const float*)d_in[4];
    const float* Wv = (const float*)d_in[5];
    const float* bv = (const float*)d_in[6];
    const float* Wo = (const float*)d_in[7];
    const float* bo = (const float*)d_in[8];

    ushort_t* qkv  = (ushort_t*)d_ws;                 // q,k [B,H,N,HD]; v [B,H,HD,N]
    ushort_t* abuf = qkv + 3 * MATE;
    ushort_t* xbf  = abuf + MATE;
    ushort_t* wqkv_t = xbf + MATE;                    // 2304*768 bf16
    ushort_t* wo_t   = wqkv_t + (size_t)3 * DIM * DIM;
    float* ball = (float*)(wo_t + (size_t)DIM * DIM); // 2304 floats

    cvt_bf16_kernel<<<(int)(MATE / 4 + 255) / 256, 256, 0, stream>>>(X, xbf, (int)(MATE / 4));
    transpose4_kernel<<<dim3(DIM / 64, DIM / 64, 4), 256, 0, stream>>>(
        Wq, Wk, Wv, Wo, wqkv_t, wo_t);
    bias_concat_kernel<<<(3 * DIM + 255) / 256, 256, 0, stream>>>(bq, bk, bv, ball);

    // QKV projection: 18 col-blocks x 128 row-blocks, XCD-swizzled 1-D
    mfma_gemm<0><<<dim3(18 * 128), 256, 0, stream>>>(xbf, wqkv_t, ball, qkv);

    attn_kernel<<<dim3((SEQ / 128) * BATCH * NH), 256, 0, stream>>>(
        qkv, qkv + MATE, qkv + 2 * MATE, abuf);

    // out projection: 6 col-blocks x 128 row-blocks, XCD-swizzled 1-D
    mfma_gemm<1><<<dim3(6 * 128), 256, 0, stream>>>(abuf, wo_t, bo, d_out);
}

// Round 11
// 327.554 us; speedup vs baseline: 1.2921x; 1.0549x over previous
//
#include <hip/hip_runtime.h>
#include <hip/hip_bf16.h>
#include <math.h>

#define DIM 768
#define NH 12
#define HD 64
#define BATCH 16
#define SEQ 1024
#define M_TOTAL (BATCH * SEQ)   // 16384
#define MATE ((size_t)M_TOTAL * DIM)  // elements per activation plane

typedef unsigned short ushort_t;
typedef __attribute__((ext_vector_type(8))) short short8;
typedef __attribute__((ext_vector_type(4))) float floatx4;

__device__ __constant__ float kScale = 0.03608439182435161f; // 1/sqrt(768)

__device__ inline ushort_t f2b(float x) {
    __hip_bfloat16 h = __float2bfloat16(x);
    return __builtin_bit_cast(ushort_t, h);
}
__device__ inline float b2f_u32(unsigned int bits16) {
    union { unsigned int i; float f; } c;
    c.i = bits16 << 16;
    return c.f;
}
__device__ inline float b2f(ushort_t u) { return b2f_u32((unsigned int)u); }

// async global->LDS, 16 B per lane; LDS dest is wave-uniform base + lane*16
__device__ __forceinline__ void gl2lds16(const ushort_t* g, ushort_t* l) {
    __builtin_amdgcn_global_load_lds(
        (__attribute__((address_space(1))) void*)g,
        (__attribute__((address_space(3))) void*)l, 16, 0, 0);
}

// ---------------------------------------------------------------------------
// fp32 -> bf16 plane
// ---------------------------------------------------------------------------
__global__ __launch_bounds__(256) void cvt_bf16_kernel(
    const float* __restrict__ X, ushort_t* __restrict__ Y, int n4)
{
    int i = blockIdx.x * 256 + threadIdx.x;
    if (i >= n4) return;
    float4 v = ((const float4*)X)[i];
    ushort4 o;
    o.x = f2b(v.x); o.y = f2b(v.y); o.z = f2b(v.z); o.w = f2b(v.w);
    ((ushort4*)Y)[i] = o;
}

// ---------------------------------------------------------------------------
// All 4 weights: W[k][n] fp32 -> transposed bf16 plane Wt[n][k].
// blockIdx.z selects the matrix (0=Wq,1=Wk,2=Wv,3=Wo).
// ---------------------------------------------------------------------------
__global__ __launch_bounds__(256) void transpose4_kernel(
    const float* __restrict__ W0, const float* __restrict__ W1,
    const float* __restrict__ W2, const float* __restrict__ W3,
    ushort_t* __restrict__ qkv_t, ushort_t* __restrict__ o_t)
{
    const int z = blockIdx.z;
    const float* W = (z == 0) ? W0 : (z == 1) ? W1 : (z == 2) ? W2 : W3;
    ushort_t* hi = (z < 3) ? qkv_t + (size_t)z * DIM * DIM : o_t;

    __shared__ float t[64][65];
    const int k0 = blockIdx.x * 64, n0 = blockIdx.y * 64;
    const int lr = threadIdx.x >> 2, lc = (threadIdx.x & 3) * 16;
    #pragma unroll
    for (int j = 0; j < 4; ++j) {
        float4 v = *(const float4*)&W[(size_t)(k0 + lr) * DIM + n0 + lc + j * 4];
        t[lr][lc + j * 4 + 0] = v.x;
        t[lr][lc + j * 4 + 1] = v.y;
        t[lr][lc + j * 4 + 2] = v.z;
        t[lr][lc + j * 4 + 3] = v.w;
    }
    __syncthreads();
    #pragma unroll
    for (int j = 0; j < 16; ++j)
        hi[(size_t)(n0 + lr) * DIM + k0 + lc + j] = f2b(t[lc + j][lr]);
}

__global__ __launch_bounds__(256) void bias_concat_kernel(
    const float* __restrict__ bq, const float* __restrict__ bk,
    const float* __restrict__ bv, float* __restrict__ ball)
{
    int i = blockIdx.x * 256 + threadIdx.x;
    if (i >= 3 * DIM) return;
    float v = (i < DIM) ? bq[i] : (i < 2 * DIM ? bk[i - DIM] : bv[i - 2 * DIM]);
    ball[i] = v;
}

// ---------------------------------------------------------------------------
// bf16 MFMA GEMM: C[M,N] = A[M,K=768](bf16) @ Wt[N,K](bf16)^T + bias
// Exact R1 structure (best measured 103.9 us).
// ---------------------------------------------------------------------------
template <int EPI>
__global__ __launch_bounds__(256) void mfma_gemm(
    const ushort_t* __restrict__ A, const ushort_t* __restrict__ Bhi,
    const float* __restrict__ bias, void* __restrict__ Cout)
{
    __shared__ ushort_t sA[128 * 32];   // 8 KB, linear pitch 32 (64 B rows)
    __shared__ ushort_t sB[128 * 32];   // 8 KB

    // XCD swizzle: rows fast within the XCD's strip, cols slow
    const int bid = blockIdx.x;
    const int xcd = bid & 7;
    const int o = bid >> 3;
    const int row0 = (xcd * 16 + (o & 15)) * 128;
    const int col0 = (o >> 4) * 128;

    const int tid = threadIdx.x;
    const int lane = tid & 63;
    const int wave = tid >> 6;
    const int wm = (wave & 1) * 64;
    const int wn = (wave >> 1) * 64;
    const int m16 = lane & 15;
    const int quad = lane >> 4;

    const int srow = lane >> 2;          // row within a 16-row group
    const int schunk = (lane & 3) * 8;   // 16 B chunk within a row (bf16 elems)

    const size_t aoff = (size_t)(row0 + wave * 32 + srow) * DIM + schunk;
    const size_t boff = (size_t)(col0 + wave * 32 + srow) * DIM + schunk;
    ushort_t* lA0 = sA + wave * 1024;    // wave-uniform LDS bases
    ushort_t* lA1 = lA0 + 512;
    ushort_t* lB0 = sB + wave * 1024;
    ushort_t* lB1 = lB0 + 512;

    floatx4 acc[4][4];
    #pragma unroll
    for (int i = 0; i < 4; ++i)
        #pragma unroll
        for (int j = 0; j < 4; ++j)
            acc[i][j] = (floatx4){0.f, 0.f, 0.f, 0.f};

    for (int k0 = 0; k0 < DIM; k0 += 32) {
        __syncthreads();   // all waves done reading previous tile
        gl2lds16(A + aoff + k0, lA0);
        gl2lds16(A + aoff + (size_t)16 * DIM + k0, lA1);
        gl2lds16(Bhi + boff + k0, lB0);
        gl2lds16(Bhi + boff + (size_t)16 * DIM + k0, lB1);
        __syncthreads();   // compiler drains vmcnt(0) before this barrier

        short8 af[4], bh[4];
        #pragma unroll
        for (int i = 0; i < 4; ++i) {
            af[i] = *(const short8*)&sA[(wm + i * 16 + m16) * 32 + quad * 8];
            bh[i] = *(const short8*)&sB[(wn + i * 16 + m16) * 32 + quad * 8];
        }
        #pragma unroll
        for (int i = 0; i < 4; ++i)
            #pragma unroll
            for (int j = 0; j < 4; ++j)
                acc[i][j] = __builtin_amdgcn_mfma_f32_16x16x32_bf16(af[i], bh[j], acc[i][j], 0, 0, 0);
    }

    if (EPI == 0) {
        const int proj = col0 / DIM;      // uniform per block (128 | 768)
        const int rem0 = col0 % DIM;
        const float sc = (proj == 0) ? kScale : 1.0f;   // pre-scale Q
        ushort_t* C = (ushort_t*)Cout + (size_t)proj * MATE;
        #pragma unroll
        for (int j = 0; j < 4; ++j) {
            const int coff = wn + j * 16 + m16;
            const int cc = rem0 + coff;
            const int h = cc >> 6, dd = cc & 63;
            const float bs = bias[col0 + coff];
            #pragma unroll
            for (int i = 0; i < 4; ++i)
                #pragma unroll
                for (int r = 0; r < 4; ++r) {
                    const int m = row0 + wm + i * 16 + quad * 4 + r;
                    const int bb = m >> 10, nn = m & 1023;
                    if (proj < 2) {
                        C[(((size_t)(bb * NH + h) * SEQ + nn) << 6) + dd] =
                            f2b((acc[i][j][r] + bs) * sc);
                    } else {
                        C[((((size_t)(bb * NH + h) << 6) + dd) << 10) + nn] =
                            f2b(acc[i][j][r] + bs);
                    }
                }
        }
    } else {
        float* C = (float*)Cout;
        #pragma unroll
        for (int j = 0; j < 4; ++j) {
            const int coff = wn + j * 16 + m16;
            const float bs = bias[col0 + coff];
            #pragma unroll
            for (int i = 0; i < 4; ++i)
                #pragma unroll
                for (int r = 0; r < 4; ++r) {
                    const int m = row0 + wm + i * 16 + quad * 4 + r;
                    C[(size_t)m * DIM + col0 + coff] = acc[i][j][r] + bs;
                }
        }
    }
}

// ---------------------------------------------------------------------------
// MFMA flash attention, bf16 in/out, fp32 accumulate. R1 staging skeleton
// (reg-prefetch K/V -> LDS, 2 barriers/tile, APK=72).
// Round-10 softmax path (keeps R9's HW-verified swapped-QK^T + l-MFMA,
// replaces the bpermute redistribution):
//   - sacc = mfma(kf, qf) -> S^T: lane holds P[query=m16][keys quad*4+r]
//     per t-subtile. P packed to bf16 pairs in registers.
//   - Lane's 4 keys per (f,t) are CONTIGUOUS in Ps[query][key] -> one
//     aligned ds_write_b64; 8 b64 writes/tile replace R1's 32 u16 scatter
//     and R9's 32 ds_bpermute (1.27e7 conflicts).
//   - PV A-frags read back R1-style (8 ds_read_b128, wave-private rows,
//     same-wave DS ordering -- R1 precedent).
//   - l via ones-column MFMA (R9-verified): lx[f] rows align with oacc;
//     exact rounded-P normalization, no sum chain, no final shfl reduce.
//   - setprio(1) around MFMA clusters (m191: +4-7% attn).
// ---------------------------------------------------------------------------
#define APK 72   // LDS row pitch (bf16): 144 B
__global__ __launch_bounds__(256) void attn_kernel(
    const ushort_t* __restrict__ Q, const ushort_t* __restrict__ K,
    const ushort_t* __restrict__ Vt, ushort_t* __restrict__ Aout)
{
    __shared__ ushort_t Ks[64 * APK];
    __shared__ ushort_t Vs[64 * APK];
    __shared__ ushort_t Ps[128 * APK];   // P tile; reused for O at the end

    const int bid = blockIdx.x;          // 1536 blocks
    const int xcd = bid & 7;
    const int o = bid >> 3;              // 0..191
    const int bh = xcd * 24 + (o >> 3);  // 24 heads per XCD
    const int q0 = (o & 7) * 128;        // q-tiles fast -> K/V L2 reuse

    const int tid = threadIdx.x;
    const int lane = tid & 63;
    const int wave = tid >> 6;
    const int wq = wave * 32;
    const int m16 = lane & 15;
    const int quad = lane >> 4;
    const size_t base  = (size_t)bh * SEQ * HD;   // Q,K: [N][HD]
    const size_t baseT = (size_t)bh * HD * SEQ;   // Vt:  [HD][N]

    const int sr = tid >> 2;            // staging row 0..63
    const int sc = (tid & 3) * 16;      // staging chunk (bf16)

    // ones B-fragment (bf16 1.0 splat) for the l-column MFMA
    short8 onesv;
    #pragma unroll
    for (int j = 0; j < 8; ++j) onesv[j] = (short)0x3F80;

    // Q fragments (B-operand of swapped QK^T)
    short8 qf[2][2];
    #pragma unroll
    for (int f = 0; f < 2; ++f)
        #pragma unroll
        for (int kc = 0; kc < 2; ++kc)
            qf[f][kc] = *(const short8*)&Q[base +
                (size_t)(q0 + wq + f * 16 + m16) * HD + kc * 32 + quad * 8];

    floatx4 oacc[2][4];
    floatx4 lx[2];                       // l accumulator (ones-column)
    #pragma unroll
    for (int f = 0; f < 2; ++f) {
        #pragma unroll
        for (int dt = 0; dt < 4; ++dt) oacc[f][dt] = (floatx4){0.f, 0.f, 0.f, 0.f};
        lx[f] = (floatx4){0.f, 0.f, 0.f, 0.f};
    }

    // prefetch tile 0
    uint4 kv0 = *(const uint4*)&K[base + (size_t)sr * HD + sc];
    uint4 kv1 = *(const uint4*)&K[base + (size_t)sr * HD + sc + 8];
    uint4 vv0 = *(const uint4*)&Vt[baseT + (size_t)sr * SEQ + sc];
    uint4 vv1 = *(const uint4*)&Vt[baseT + (size_t)sr * SEQ + sc + 8];

    for (int kt = 0; kt < SEQ / 64; ++kt) {
        __syncthreads();   // all waves done reading prev Ks/Vs
        *(uint4*)&Ks[sr * APK + sc] = kv0;
        *(uint4*)&Ks[sr * APK + sc + 8] = kv1;
        *(uint4*)&Vs[sr * APK + sc] = vv0;
        *(uint4*)&Vs[sr * APK + sc + 8] = vv1;
        __syncthreads();
        if (kt + 1 < SEQ / 64) {   // prefetch next tile (overlaps compute)
            const int k1 = (kt + 1) * 64;
            kv0 = *(const uint4*)&K[base + (size_t)(k1 + sr) * HD + sc];
            kv1 = *(const uint4*)&K[base + (size_t)(k1 + sr) * HD + sc + 8];
            vv0 = *(const uint4*)&Vt[baseT + (size_t)sr * SEQ + k1 + sc];
            vv1 = *(const uint4*)&Vt[baseT + (size_t)sr * SEQ + k1 + sc + 8];
        }

        // S^T = K Q^T (swapped): lane's column = its own query m16
        short8 kf[2][4];
        #pragma unroll
        for (int kc = 0; kc < 2; ++kc)
            #pragma unroll
            for (int t = 0; t < 4; ++t)
                kf[kc][t] = *(const short8*)&Ks[(t * 16 + m16) * APK + kc * 32 + quad * 8];
        floatx4 sacc[2][4];
        #pragma unroll
        for (int f = 0; f < 2; ++f)
            #pragma unroll
            for (int t = 0; t < 4; ++t)
                sacc[f][t] = (floatx4){0.f, 0.f, 0.f, 0.f};
        __builtin_amdgcn_s_setprio(1);
        #pragma unroll
        for (int kc = 0; kc < 2; ++kc)
            #pragma unroll
            for (int f = 0; f < 2; ++f)
                #pragma unroll
                for (int t = 0; t < 4; ++t)
                    sacc[f][t] = __builtin_amdgcn_mfma_f32_16x16x32_bf16(
                        kf[kc][t], qf[f][kc], sacc[f][t], 0, 0, 0);
        __builtin_amdgcn_s_setprio(0);

        // max-free softmax in registers: p = exp(s), bf16 pairs; lane's 4
        // keys per (f,t) are contiguous -> ONE aligned ds_write_b64 each.
        #pragma unroll
        for (int f = 0; f < 2; ++f)
            #pragma unroll
            for (int t = 0; t < 4; ++t) {
                ushort2 w0, w1;
                w0.x = f2b(__expf(sacc[f][t][0]));
                w0.y = f2b(__expf(sacc[f][t][1]));
                w1.x = f2b(__expf(sacc[f][t][2]));
                w1.y = f2b(__expf(sacc[f][t][3]));
                uint2 pr;
                pr.x = __builtin_bit_cast(unsigned, w0);
                pr.y = __builtin_bit_cast(unsigned, w1);
                *(uint2*)&Ps[(wq + f * 16 + m16) * APK + t * 16 + quad * 4] = pr;
            }

        // V fragments
        short8 vf[2][4];
        #pragma unroll
        for (int kc = 0; kc < 2; ++kc)
            #pragma unroll
            for (int dt = 0; dt < 4; ++dt)
                vf[kc][dt] = *(const short8*)&Vs[(dt * 16 + m16) * APK + kc * 32 + quad * 8];

        // O += P V (P read back b128, wave-private rows); l += P * ones
        __builtin_amdgcn_s_setprio(1);
        #pragma unroll
        for (int f = 0; f < 2; ++f) {
            #pragma unroll
            for (int kc = 0; kc < 2; ++kc) {
                short8 pf = *(const short8*)&Ps[(wq + f * 16 + m16) * APK + kc * 32 + quad * 8];
                #pragma unroll
                for (int dt = 0; dt < 4; ++dt)
                    oacc[f][dt] = __builtin_amdgcn_mfma_f32_16x16x32_bf16(
                        pf, vf[kc][dt], oacc[f][dt], 0, 0, 0);
                lx[f] = __builtin_amdgcn_mfma_f32_16x16x32_bf16(
                    pf, onesv, lx[f], 0, 0, 0);
            }
        }
        __builtin_amdgcn_s_setprio(0);
    }

    // normalize: lx[f][r] = l for query wq+f*16+quad*4+r (aligned with oacc)
    float inv[2][4];
    #pragma unroll
    for (int f = 0; f < 2; ++f)
        #pragma unroll
        for (int r = 0; r < 4; ++r)
            inv[f][r] = 1.0f / lx[f][r];

    __syncthreads();   // all waves done with P reads before O overwrites Ps

    // stage O (bf16) into Ps [q][d] (wave-private rows), then coalesced store
    #pragma unroll
    for (int f = 0; f < 2; ++f)
        #pragma unroll
        for (int dt = 0; dt < 4; ++dt)
            #pragma unroll
            for (int r = 0; r < 4; ++r)
                Ps[(wq + f * 16 + quad * 4 + r) * APK + dt * 16 + m16] =
                    f2b(oacc[f][dt][r] * inv[f][r]);
    __syncthreads();

    const int b = bh / NH, h = bh % NH;
    const int orow = tid >> 1;             // 0..127
    const int oc = (tid & 1) * 32;         // bf16 offset
    const size_t row = (size_t)b * SEQ + q0 + orow;
    #pragma unroll
    for (int j = 0; j < 4; ++j) {
        uint4 ov = *(const uint4*)&Ps[orow * APK + oc + j * 8];
        *(uint4*)&Aout[row * DIM + h * HD + oc + j * 8] = ov;
    }
}

extern "C" void kernel_launch(void* const* d_in, const int* in_sizes, int n_in,
                              void* d_out, int out_size, void* d_ws, size_t ws_size,
                              hipStream_t stream)
{
    const float* X  = (const float*)d_in[0];
    const float* Wq = (const float*)d_in[1];
    const float* bq = (const float*)d_in[2];
    const float* Wk = (const float*)d_in[3];
    const float* bk = (const float*)d_in[4];
    const float* Wv = (const float*)d_in[5];
    const float* bv = (const float*)d_in[6];
    const float* Wo = (const float*)d_in[7];
    const float* bo = (const float*)d_in[8];

    ushort_t* qkv  = (ushort_t*)d_ws;                 // q,k [B,H,N,HD]; v [B,H,HD,N]
    ushort_t* abuf = qkv + 3 * MATE;
    ushort_t* xbf  = abuf + MATE;
    ushort_t* wqkv_t = xbf + MATE;                    // 2304*768 bf16
    ushort_t* wo_t   = wqkv_t + (size_t)3 * DIM * DIM;
    float* ball = (float*)(wo_t + (size_t)DIM * DIM); // 2304 floats

    cvt_bf16_kernel<<<(int)(MATE / 4 + 255) / 256, 256, 0, stream>>>(X, xbf, (int)(MATE / 4));
    transpose4_kernel<<<dim3(DIM / 64, DIM / 64, 4), 256, 0, stream>>>(
        Wq, Wk, Wv, Wo, wqkv_t, wo_t);
    bias_concat_kernel<<<(3 * DIM + 255) / 256, 256, 0, stream>>>(bq, bk, bv, ball);

    // QKV projection: 18 col-blocks x 128 row-blocks, XCD-swizzled 1-D
    mfma_gemm<0><<<dim3(18 * 128), 256, 0, stream>>>(xbf, wqkv_t, ball, qkv);

    attn_kernel<<<dim3((SEQ / 128) * BATCH * NH), 256, 0, stream>>>(
        qkv, qkv + MATE, qkv + 2 * MATE, abuf);

    // out projection: 6 col-blocks x 128 row-blocks, XCD-swizzled 1-D
    mfma_gemm<1><<<dim3(6 * 128), 256, 0, stream>>>(abuf, wo_t, bo, d_out);
}

// Round 12
// 326.210 us; speedup vs baseline: 1.2975x; 1.0041x over previous
//
#include <hip/hip_runtime.h>
#include <hip/hip_bf16.h>
#include <math.h>

#define DIM 768
#define NH 12
#define HD 64
#define BATCH 16
#define SEQ 1024
#define M_TOTAL (BATCH * SEQ)   // 16384
#define MATE ((size_t)M_TOTAL * DIM)  // elements per activation plane

typedef unsigned short ushort_t;
typedef __attribute__((ext_vector_type(8))) short short8;
typedef __attribute__((ext_vector_type(4))) float floatx4;

__device__ __constant__ float kScale = 0.03608439182435161f; // 1/sqrt(768)

__device__ inline ushort_t f2b(float x) {
    __hip_bfloat16 h = __float2bfloat16(x);
    return __builtin_bit_cast(ushort_t, h);
}
__device__ inline float b2f_u32(unsigned int bits16) {
    union { unsigned int i; float f; } c;
    c.i = bits16 << 16;
    return c.f;
}
__device__ inline float b2f(ushort_t u) { return b2f_u32((unsigned int)u); }

// async global->LDS, 16 B per lane; LDS dest is wave-uniform base + lane*16
__device__ __forceinline__ void gl2lds16(const ushort_t* g, ushort_t* l) {
    __builtin_amdgcn_global_load_lds(
        (__attribute__((address_space(1))) void*)g,
        (__attribute__((address_space(3))) void*)l, 16, 0, 0);
}

// ---------------------------------------------------------------------------
// Fused prep: fp32->bf16 activation plane + 4 weight transposes + bias concat.
// Block-range split (all parts independent; branch is block-uniform).
//   blocks [0, 12288)            : cvt  (MATE/4 float4 elements, exact fit)
//   blocks [12288, 12288+576)    : transpose (z = t/144, 12x12 64-tiles)
//   blocks [12864, 12873)        : bias concat (2304 floats)
// (verified correct in R4)
// ---------------------------------------------------------------------------
#define NCVT 12288
__global__ __launch_bounds__(256) void prep_kernel(
    const float* __restrict__ X, ushort_t* __restrict__ Y,
    const float* __restrict__ W0, const float* __restrict__ W1,
    const float* __restrict__ W2, const float* __restrict__ W3,
    ushort_t* __restrict__ qkv_t, ushort_t* __restrict__ o_t,
    const float* __restrict__ bq, const float* __restrict__ bk,
    const float* __restrict__ bv, float* __restrict__ ball)
{
    __shared__ float t[64][65];
    const int b = blockIdx.x;
    if (b < NCVT) {
        const int i = b * 256 + threadIdx.x;
        float4 v = ((const float4*)X)[i];
        ushort4 o;
        o.x = f2b(v.x); o.y = f2b(v.y); o.z = f2b(v.z); o.w = f2b(v.w);
        ((ushort4*)Y)[i] = o;
        return;
    }
    if (b < NCVT + 576) {
        const int tt = b - NCVT;
        const int z = tt / 144, rem = tt % 144;
        const float* W = (z == 0) ? W0 : (z == 1) ? W1 : (z == 2) ? W2 : W3;
        ushort_t* hi = (z < 3) ? qkv_t + (size_t)z * DIM * DIM : o_t;
        const int k0 = (rem / 12) * 64, n0 = (rem % 12) * 64;
        const int lr = threadIdx.x >> 2, lc = (threadIdx.x & 3) * 16;
        #pragma unroll
        for (int j = 0; j < 4; ++j) {
            float4 v = *(const float4*)&W[(size_t)(k0 + lr) * DIM + n0 + lc + j * 4];
            t[lr][lc + j * 4 + 0] = v.x;
            t[lr][lc + j * 4 + 1] = v.y;
            t[lr][lc + j * 4 + 2] = v.z;
            t[lr][lc + j * 4 + 3] = v.w;
        }
        __syncthreads();
        #pragma unroll
        for (int j = 0; j < 16; ++j)
            hi[(size_t)(n0 + lr) * DIM + k0 + lc + j] = f2b(t[lc + j][lr]);
        return;
    }
    const int i = (b - NCVT - 576) * 256 + threadIdx.x;
    if (i >= 3 * DIM) return;
    ball[i] = (i < DIM) ? bq[i] : (i < 2 * DIM ? bk[i - DIM] : bv[i - 2 * DIM]);
}

// ---------------------------------------------------------------------------
// bf16 MFMA GEMM: C[M,N] = A[M,K=768](bf16) @ Wt[N,K](bf16)^T + bias
// Exact R1 structure (best measured 103.9 us).
// ---------------------------------------------------------------------------
template <int EPI>
__global__ __launch_bounds__(256) void mfma_gemm(
    const ushort_t* __restrict__ A, const ushort_t* __restrict__ Bhi,
    const float* __restrict__ bias, void* __restrict__ Cout)
{
    __shared__ ushort_t sA[128 * 32];   // 8 KB, linear pitch 32 (64 B rows)
    __shared__ ushort_t sB[128 * 32];   // 8 KB

    // XCD swizzle: rows fast within the XCD's strip, cols slow
    const int bid = blockIdx.x;
    const int xcd = bid & 7;
    const int o = bid >> 3;
    const int row0 = (xcd * 16 + (o & 15)) * 128;
    const int col0 = (o >> 4) * 128;

    const int tid = threadIdx.x;
    const int lane = tid & 63;
    const int wave = tid >> 6;
    const int wm = (wave & 1) * 64;
    const int wn = (wave >> 1) * 64;
    const int m16 = lane & 15;
    const int quad = lane >> 4;

    const int srow = lane >> 2;          // row within a 16-row group
    const int schunk = (lane & 3) * 8;   // 16 B chunk within a row (bf16 elems)

    const size_t aoff = (size_t)(row0 + wave * 32 + srow) * DIM + schunk;
    const size_t boff = (size_t)(col0 + wave * 32 + srow) * DIM + schunk;
    ushort_t* lA0 = sA + wave * 1024;    // wave-uniform LDS bases
    ushort_t* lA1 = lA0 + 512;
    ushort_t* lB0 = sB + wave * 1024;
    ushort_t* lB1 = lB0 + 512;

    floatx4 acc[4][4];
    #pragma unroll
    for (int i = 0; i < 4; ++i)
        #pragma unroll
        for (int j = 0; j < 4; ++j)
            acc[i][j] = (floatx4){0.f, 0.f, 0.f, 0.f};

    for (int k0 = 0; k0 < DIM; k0 += 32) {
        __syncthreads();   // all waves done reading previous tile
        gl2lds16(A + aoff + k0, lA0);
        gl2lds16(A + aoff + (size_t)16 * DIM + k0, lA1);
        gl2lds16(Bhi + boff + k0, lB0);
        gl2lds16(Bhi + boff + (size_t)16 * DIM + k0, lB1);
        __syncthreads();   // compiler drains vmcnt(0) before this barrier

        short8 af[4], bh[4];
        #pragma unroll
        for (int i = 0; i < 4; ++i) {
            af[i] = *(const short8*)&sA[(wm + i * 16 + m16) * 32 + quad * 8];
            bh[i] = *(const short8*)&sB[(wn + i * 16 + m16) * 32 + quad * 8];
        }
        #pragma unroll
        for (int i = 0; i < 4; ++i)
            #pragma unroll
            for (int j = 0; j < 4; ++j)
                acc[i][j] = __builtin_amdgcn_mfma_f32_16x16x32_bf16(af[i], bh[j], acc[i][j], 0, 0, 0);
    }

    if (EPI == 0) {
        const int proj = col0 / DIM;      // uniform per block (128 | 768)
        const int rem0 = col0 % DIM;
        const float sc = (proj == 0) ? kScale : 1.0f;   // pre-scale Q
        ushort_t* C = (ushort_t*)Cout + (size_t)proj * MATE;
        #pragma unroll
        for (int j = 0; j < 4; ++j) {
            const int coff = wn + j * 16 + m16;
            const int cc = rem0 + coff;
            const int h = cc >> 6, dd = cc & 63;
            const float bs = bias[col0 + coff];
            #pragma unroll
            for (int i = 0; i < 4; ++i)
                #pragma unroll
                for (int r = 0; r < 4; ++r) {
                    const int m = row0 + wm + i * 16 + quad * 4 + r;
                    const int bb = m >> 10, nn = m & 1023;
                    if (proj < 2) {
                        C[(((size_t)(bb * NH + h) * SEQ + nn) << 6) + dd] =
                            f2b((acc[i][j][r] + bs) * sc);
                    } else {
                        C[((((size_t)(bb * NH + h) << 6) + dd) << 10) + nn] =
                            f2b(acc[i][j][r] + bs);
                    }
                }
        }
    } else {
        float* C = (float*)Cout;
        #pragma unroll
        for (int j = 0; j < 4; ++j) {
            const int coff = wn + j * 16 + m16;
            const float bs = bias[col0 + coff];
            #pragma unroll
            for (int i = 0; i < 4; ++i)
                #pragma unroll
                for (int r = 0; r < 4; ++r) {
                    const int m = row0 + wm + i * 16 + quad * 4 + r;
                    C[(size_t)m * DIM + col0 + coff] = acc[i][j][r] + bs;
                }
        }
    }
}

// ---------------------------------------------------------------------------
// MFMA flash attention, bf16 in/out, fp32 accumulate. R1 staging skeleton
// (reg-prefetch K/V -> LDS, 2 barriers/tile, APK=72).
// R10/R11 softmax path (HW-verified):
//   - sacc = mfma(kf, qf) -> S^T: lane holds P[query=m16][keys quad*4+r]
//     per t-subtile; P packed to bf16 pairs, stored with ONE aligned
//     ds_write_b64 per (f,t) -- no scalar scatter, no bpermute.
//   - PV A-frags read back b128 (wave-private rows).
//   - l via ones-column MFMA: lx[f] rows align with oacc; exact rounded-P
//     normalization, no sum chain, no final shfl reduce.
//   - setprio(1) around MFMA clusters.
// ---------------------------------------------------------------------------
#define APK 72   // LDS row pitch (bf16): 144 B
__global__ __launch_bounds__(256) void attn_kernel(
    const ushort_t* __restrict__ Q, const ushort_t* __restrict__ K,
    const ushort_t* __restrict__ Vt, ushort_t* __restrict__ Aout)
{
    __shared__ ushort_t Ks[64 * APK];
    __shared__ ushort_t Vs[64 * APK];
    __shared__ ushort_t Ps[128 * APK];   // P tile; reused for O at the end

    const int bid = blockIdx.x;          // 1536 blocks
    const int xcd = bid & 7;
    const int o = bid >> 3;              // 0..191
    const int bh = xcd * 24 + (o >> 3);  // 24 heads per XCD
    const int q0 = (o & 7) * 128;        // q-tiles fast -> K/V L2 reuse

    const int tid = threadIdx.x;
    const int lane = tid & 63;
    const int wave = tid >> 6;
    const int wq = wave * 32;
    const int m16 = lane & 15;
    const int quad = lane >> 4;
    const size_t base  = (size_t)bh * SEQ * HD;   // Q,K: [N][HD]
    const size_t baseT = (size_t)bh * HD * SEQ;   // Vt:  [HD][N]

    const int sr = tid >> 2;            // staging row 0..63
    const int sc = (tid & 3) * 16;      // staging chunk (bf16)

    // ones B-fragment (bf16 1.0 splat) for the l-column MFMA
    short8 onesv;
    #pragma unroll
    for (int j = 0; j < 8; ++j) onesv[j] = (short)0x3F80;

    // Q fragments (B-operand of swapped QK^T)
    short8 qf[2][2];
    #pragma unroll
    for (int f = 0; f < 2; ++f)
        #pragma unroll
        for (int kc = 0; kc < 2; ++kc)
            qf[f][kc] = *(const short8*)&Q[base +
                (size_t)(q0 + wq + f * 16 + m16) * HD + kc * 32 + quad * 8];

    floatx4 oacc[2][4];
    floatx4 lx[2];                       // l accumulator (ones-column)
    #pragma unroll
    for (int f = 0; f < 2; ++f) {
        #pragma unroll
        for (int dt = 0; dt < 4; ++dt) oacc[f][dt] = (floatx4){0.f, 0.f, 0.f, 0.f};
        lx[f] = (floatx4){0.f, 0.f, 0.f, 0.f};
    }

    // prefetch tile 0
    uint4 kv0 = *(const uint4*)&K[base + (size_t)sr * HD + sc];
    uint4 kv1 = *(const uint4*)&K[base + (size_t)sr * HD + sc + 8];
    uint4 vv0 = *(const uint4*)&Vt[baseT + (size_t)sr * SEQ + sc];
    uint4 vv1 = *(const uint4*)&Vt[baseT + (size_t)sr * SEQ + sc + 8];

    for (int kt = 0; kt < SEQ / 64; ++kt) {
        __syncthreads();   // all waves done reading prev Ks/Vs
        *(uint4*)&Ks[sr * APK + sc] = kv0;
        *(uint4*)&Ks[sr * APK + sc + 8] = kv1;
        *(uint4*)&Vs[sr * APK + sc] = vv0;
        *(uint4*)&Vs[sr * APK + sc + 8] = vv1;
        __syncthreads();
        if (kt + 1 < SEQ / 64) {   // prefetch next tile (overlaps compute)
            const int k1 = (kt + 1) * 64;
            kv0 = *(const uint4*)&K[base + (size_t)(k1 + sr) * HD + sc];
            kv1 = *(const uint4*)&K[base + (size_t)(k1 + sr) * HD + sc + 8];
            vv0 = *(const uint4*)&Vt[baseT + (size_t)sr * SEQ + k1 + sc];
            vv1 = *(const uint4*)&Vt[baseT + (size_t)sr * SEQ + k1 + sc + 8];
        }

        // S^T = K Q^T (swapped): lane's column = its own query m16
        short8 kf[2][4];
        #pragma unroll
        for (int kc = 0; kc < 2; ++kc)
            #pragma unroll
            for (int t = 0; t < 4; ++t)
                kf[kc][t] = *(const short8*)&Ks[(t * 16 + m16) * APK + kc * 32 + quad * 8];
        floatx4 sacc[2][4];
        #pragma unroll
        for (int f = 0; f < 2; ++f)
            #pragma unroll
            for (int t = 0; t < 4; ++t)
                sacc[f][t] = (floatx4){0.f, 0.f, 0.f, 0.f};
        __builtin_amdgcn_s_setprio(1);
        #pragma unroll
        for (int kc = 0; kc < 2; ++kc)
            #pragma unroll
            for (int f = 0; f < 2; ++f)
                #pragma unroll
                for (int t = 0; t < 4; ++t)
                    sacc[f][t] = __builtin_amdgcn_mfma_f32_16x16x32_bf16(
                        kf[kc][t], qf[f][kc], sacc[f][t], 0, 0, 0);
        __builtin_amdgcn_s_setprio(0);

        // max-free softmax in registers: p = exp(s), bf16 pairs; lane's 4
        // keys per (f,t) are contiguous -> ONE aligned ds_write_b64 each.
        #pragma unroll
        for (int f = 0; f < 2; ++f)
            #pragma unroll
            for (int t = 0; t < 4; ++t) {
                ushort2 w0, w1;
                w0.x = f2b(__expf(sacc[f][t][0]));
                w0.y = f2b(__expf(sacc[f][t][1]));
                w1.x = f2b(__expf(sacc[f][t][2]));
                w1.y = f2b(__expf(sacc[f][t][3]));
                uint2 pr;
                pr.x = __builtin_bit_cast(unsigned, w0);
                pr.y = __builtin_bit_cast(unsigned, w1);
                *(uint2*)&Ps[(wq + f * 16 + m16) * APK + t * 16 + quad * 4] = pr;
            }

        // V fragments
        short8 vf[2][4];
        #pragma unroll
        for (int kc = 0; kc < 2; ++kc)
            #pragma unroll
            for (int dt = 0; dt < 4; ++dt)
                vf[kc][dt] = *(const short8*)&Vs[(dt * 16 + m16) * APK + kc * 32 + quad * 8];

        // O += P V (P read back b128, wave-private rows); l += P * ones
        __builtin_amdgcn_s_setprio(1);
        #pragma unroll
        for (int f = 0; f < 2; ++f) {
            #pragma unroll
            for (int kc = 0; kc < 2; ++kc) {
                short8 pf = *(const short8*)&Ps[(wq + f * 16 + m16) * APK + kc * 32 + quad * 8];
                #pragma unroll
                for (int dt = 0; dt < 4; ++dt)
                    oacc[f][dt] = __builtin_amdgcn_mfma_f32_16x16x32_bf16(
                        pf, vf[kc][dt], oacc[f][dt], 0, 0, 0);
                lx[f] = __builtin_amdgcn_mfma_f32_16x16x32_bf16(
                    pf, onesv, lx[f], 0, 0, 0);
            }
        }
        __builtin_amdgcn_s_setprio(0);
    }

    // normalize: lx[f][r] = l for query wq+f*16+quad*4+r (aligned with oacc)
    float inv[2][4];
    #pragma unroll
    for (int f = 0; f < 2; ++f)
        #pragma unroll
        for (int r = 0; r < 4; ++r)
            inv[f][r] = 1.0f / lx[f][r];

    __syncthreads();   // all waves done with P reads before O overwrites Ps

    // stage O (bf16) into Ps [q][d] (wave-private rows), then coalesced store
    #pragma unroll
    for (int f = 0; f < 2; ++f)
        #pragma unroll
        for (int dt = 0; dt < 4; ++dt)
            #pragma unroll
            for (int r = 0; r < 4; ++r)
                Ps[(wq + f * 16 + quad * 4 + r) * APK + dt * 16 + m16] =
                    f2b(oacc[f][dt][r] * inv[f][r]);
    __syncthreads();

    const int b = bh / NH, h = bh % NH;
    const int orow = tid >> 1;             // 0..127
    const int oc = (tid & 1) * 32;         // bf16 offset
    const size_t row = (size_t)b * SEQ + q0 + orow;
    #pragma unroll
    for (int j = 0; j < 4; ++j) {
        uint4 ov = *(const uint4*)&Ps[orow * APK + oc + j * 8];
        *(uint4*)&Aout[row * DIM + h * HD + oc + j * 8] = ov;
    }
}

extern "C" void kernel_launch(void* const* d_in, const int* in_sizes, int n_in,
                              void* d_out, int out_size, void* d_ws, size_t ws_size,
                              hipStream_t stream)
{
    const float* X  = (const float*)d_in[0];
    const float* Wq = (const float*)d_in[1];
    const float* bq = (const float*)d_in[2];
    const float* Wk = (const float*)d_in[3];
    const float* bk = (const float*)d_in[4];
    const float* Wv = (const float*)d_in[5];
    const float* bv = (const float*)d_in[6];
    const float* Wo = (const float*)d_in[7];
    const float* bo = (const float*)d_in[8];

    ushort_t* qkv  = (ushort_t*)d_ws;                 // q,k [B,H,N,HD]; v [B,H,HD,N]
    ushort_t* abuf = qkv + 3 * MATE;
    ushort_t* xbf  = abuf + MATE;
    ushort_t* wqkv_t = xbf + MATE;                    // 2304*768 bf16
    ushort_t* wo_t   = wqkv_t + (size_t)3 * DIM * DIM;
    float* ball = (float*)(wo_t + (size_t)DIM * DIM); // 2304 floats

    // fused prep: cvt (12288 blocks) + transposes (576) + bias (9)
    prep_kernel<<<dim3(NCVT + 576 + 9), 256, 0, stream>>>(
        X, xbf, Wq, Wk, Wv, Wo, wqkv_t, wo_t, bq, bk, bv, ball);

    // QKV projection: 18 col-blocks x 128 row-blocks, XCD-swizzled 1-D
    mfma_gemm<0><<<dim3(18 * 128), 256, 0, stream>>>(xbf, wqkv_t, ball, qkv);

    attn_kernel<<<dim3((SEQ / 128) * BATCH * NH), 256, 0, stream>>>(
        qkv, qkv + MATE, qkv + 2 * MATE, abuf);

    // out projection: 6 col-blocks x 128 row-blocks, XCD-swizzled 1-D
    mfma_gemm<1><<<dim3(6 * 128), 256, 0, stream>>>(abuf, wo_t, bo, d_out);
}